// Round 9
// baseline (105.597 us; speedup 1.0000x reference)
//
#include <hip/hip_runtime.h>
#include <math.h>

// Problem constants (reference: N=16384, D=128, T=0.07)
#define NROWS 16384
#define DDIM  128
constexpr float TEMP = 0.07f;
// Pre-scale trick: x *= sqrt(log2(e)/T) so MFMA emits acc = S*<xi,xj> and
// row_lse = ln(sum exp2(acc)). The DIAGONAL (sim_ii = 1 exactly, rows unit
// norm) is masked out of the MFMA path and added analytically in finalize:
// rowsum_i = offdiag_fp8_sum_i + 2^S. Off-diag is only ~2.3% of rowsum, so
// fp8 e4m3 error there is damped ~44x -> absmax ~0.006 vs threshold 0.286.
constexpr float S_EXP = 1.44269504088896f / TEMP;  // 20.6099291

typedef __attribute__((ext_vector_type(4))) float f32x4;

// Convert + pre-scale to fp8 e4m3, writing a FRAGMENT-PACKED layout:
// byte addr = panel*16384 + ct_h*2048 + kt*512 + q*128 + l15*8 + b where
// row = panel*128 + ct_h*16 + l15, k = kt*32 + q*8 + b. A wave's MFMA
// fragment load (lane = q*16+l15, 8 B/lane) is then ONE contiguous 512 B
// global_load_dwordx2 -> 8 cache lines/instr, L1-shareable across waves.
__global__ void convert_k(const float* __restrict__ x, unsigned char* __restrict__ xbp,
                          float* __restrict__ accum, int* __restrict__ cnt) {
  const float R = 4.53981419f;  // sqrt(S_EXP); |x*R| <= ~1.3, well inside e4m3 range
  const int gid = blockIdx.x * blockDim.x + threadIdx.x;
  const int i = gid * 4;
  float4 v = *(const float4*)(x + i);
  int p = __builtin_amdgcn_cvt_pk_fp8_f32(v.x * R, v.y * R, 0, false);
  p = __builtin_amdgcn_cvt_pk_fp8_f32(v.z * R, v.w * R, p, true);
  const int row = i >> 7, k0 = i & 127;
  const int panel = row >> 7, c7 = row & 127;
  const int cth = c7 >> 4, l15 = c7 & 15;
  const int kt = k0 >> 5, q = (k0 >> 3) & 3, b = k0 & 7;  // b in {0,4}
  *(int*)(xbp + ((size_t)panel << 14) + (cth << 11) + (kt << 9) + (q << 7) +
          (l15 << 3) + b) = p;
  if (gid == 0) { *accum = 0.f; *cnt = 0; }
}

// Triangular Gram in fp8 — ROUND-9: 256-THREAD COLUMN-SPLIT BLOCKS.
// r8 (zero-barrier loop) proved neither delivery nor sync binds; the
// persistent ~25-34% occupancy (~2 waves/SIMD: ONE resident 512-thr block
// per CU, total VGPR+AGPR/wave likely ~116-160 in the unified file) caps
// MFMA<->VALU cross-wave overlap. Fix: block = (I, ci, s) with 4 waves
// (256 thr); wave w: rows w*32, cols ci*64. Per-wave work and registers
// unchanged; residency granularity 4 waves -> 3-4 blocks/CU = 12-16
// waves/CU. Column split keeps colpart single-writer (block owns 64 cols
// of the J-panel) and deletes the chalf row-exchange: each wave stores its
// 32 row-sums directly; rowpart has 16 (ci,s) slices.
// Zero barriers in the tile loop (r8 structure): per-tile per-wave private
// csbuf[ti][w][64] slots, single epilogue barrier before colpart stores.
// B/A fragments load directly from the packed layout (one contiguous
// 512 B dwordx2 per fragment, L2-resident 2 MB).
// Block (I,ci,s): d-tiles s==0: d=0..8 else 8s+1..8s+8. Tile (I,d),
// J=(I+d)%128. d==0 diag masked; d in {0,64} col-slices skipped (mirror).
__global__ __launch_bounds__(256, 4)
void gram_tri_k(const unsigned char* __restrict__ xbp, float* __restrict__ rowpart,
                float* __restrict__ colpart) {
  __shared__ float csbuf[9][4][64];  // 9 KB: per-(tile,wave) col partials

  const int tid = threadIdx.x;
  const int w = tid >> 6, lane = tid & 63;
  const int l15 = lane & 15, q = lane >> 4;
  const int I = (int)(blockIdx.x >> 4);
  const int ci = (int)((blockIdx.x >> 3) & 1);
  const int s = (int)(blockIdx.x & 7);
  const int rI = I * 128;
  const int dstart = (s == 0) ? 0 : 8 * s + 1;
  const int ntiles = (s == 0) ? 9 : 8;

  // A frags: rows w*32 + rt*16 + l15 -> packed ct_h = w*2 + rt; 8 B/lane
  long af[2][4];
  const unsigned char* gA = xbp + ((size_t)I << 14) + ((w * 2) << 11) + lane * 8;
#pragma unroll
  for (int rt = 0; rt < 2; ++rt)
#pragma unroll
    for (int kt = 0; kt < 4; ++kt)
      af[rt][kt] = *(const long*)(gA + (rt << 11) + (kt << 9));

  // B lane base: cols ci*64 + ct*16 + l15 -> packed ct_h = ci*4 + ct
  const unsigned char* gBlane = xbp + ((ci * 4) << 11) + lane * 8;

  float rs[2][4];
#pragma unroll
  for (int rt = 0; rt < 2; ++rt)
#pragma unroll
    for (int r = 0; r < 4; ++r) rs[rt][r] = 0.f;

  for (int ti = 0; ti < ntiles; ++ti) {
    const int d = dstart + ti;
    const unsigned char* gB = gBlane + ((size_t)((I + d) & 127) << 14);
    const bool dz = (d == 0);  // uniform; only s==0/ti==0 blocks pay the mask

    float cstile[4];
#pragma unroll
    for (int ct = 0; ct < 4; ++ct) {
      long bfr[4];
#pragma unroll
      for (int kt = 0; kt < 4; ++kt)
        bfr[kt] = *(const long*)(gB + (ct << 11) + (kt << 9));
      const int colb = ci * 64 + ct * 16 + l15;
      float csl = 0.f;
#pragma unroll
      for (int rt = 0; rt < 2; ++rt) {
        f32x4 a = {0.f, 0.f, 0.f, 0.f};
#pragma unroll
        for (int kt = 0; kt < 4; ++kt)
          a = __builtin_amdgcn_mfma_f32_16x16x32_fp8_fp8(af[rt][kt], bfr[kt], a, 0, 0, 0);
        // C/D layout (dtype-independent): col = l15, row = q*4 + r
#pragma unroll
        for (int r = 0; r < 4; ++r) {
          float e = __builtin_amdgcn_exp2f(a[r]);
          if (dz && (w * 32 + rt * 16 + q * 4 + r) == colb) e = 0.f;  // mask diag
          rs[rt][r] += e;
          csl += e;
        }
      }
      cstile[ct] = csl;
    }
    // col partial: reduce over q (wave's 32 rows), write this wave's
    // PRIVATE slot for this tile. No sync: unique writer, never reused;
    // consumed only after the epilogue barrier.
#pragma unroll
    for (int m = 16; m <= 32; m <<= 1)
#pragma unroll
      for (int ct = 0; ct < 4; ++ct)
        cstile[ct] += __shfl_xor(cstile[ct], m, 64);
    if (q == 0) {
#pragma unroll
      for (int ct = 0; ct < 4; ++ct)
        csbuf[ti][w][ct * 16 + l15] = cstile[ct];
    }
  }

  // rows: reduce over the 16 cols (l15) within the wave's 64-col half,
  // then store directly — no cross-wave exchange needed (col split).
#pragma unroll
  for (int m = 1; m <= 8; m <<= 1)
#pragma unroll
    for (int rt = 0; rt < 2; ++rt)
#pragma unroll
      for (int r = 0; r < 4; ++r)
        rs[rt][r] += __shfl_xor(rs[rt][r], m, 64);
  if (l15 == 0) {
#pragma unroll
    for (int rt = 0; rt < 2; ++rt)
#pragma unroll
      for (int r = 0; r < 4; ++r)
        rowpart[(size_t)(ci * 8 + s) * NROWS + rI + w * 32 + rt * 16 + q * 4 + r] =
            rs[rt][r];
  }

  __syncthreads();  // THE ONLY barrier: all csbuf slots complete

  // colpart stores: (ti, col) entries over this block's 64 cols, d not in {0,64}
  for (int e = tid; e < ntiles * 64; e += 256) {
    const int ti = e >> 6, col = e & 63;
    const int d = dstart + ti;
    if (d != 0 && d != 64)
      colpart[(size_t)(d - 1) * NROWS + ((I + d) & 127) * 128 + ci * 64 + col] =
          csbuf[ti][0][col] + csbuf[ti][1][col] + csbuf[ti][2][col] + csbuf[ti][3][col];
  }
}

// 64 blocks x 64 threads, 4 rows/thread via float4: sums 16 rowpart +
// 63 colpart slices, adds the analytic diagonal 2^S, logs, wave-reduces.
__global__ void finalize_k(const float* __restrict__ rowpart, const float* __restrict__ colpart,
                           float* __restrict__ accum, int* __restrict__ cnt,
                           float* __restrict__ out) {
  const int tid = threadIdx.x;
  const size_t i4 = (size_t)(blockIdx.x * 64 + tid) * 4;
  const float DIAG = __builtin_exp2f(S_EXP);  // exact e^{1/T}, rows unit-norm
  float4 v = {DIAG, DIAG, DIAG, DIAG};
#pragma unroll
  for (int s2 = 0; s2 < 16; ++s2) {
    float4 t = *(const float4*)&rowpart[(size_t)s2 * NROWS + i4];
    v.x += t.x; v.y += t.y; v.z += t.z; v.w += t.w;
  }
#pragma unroll
  for (int d = 1; d < 64; ++d) {
    float4 t = *(const float4*)&colpart[(size_t)(d - 1) * NROWS + i4];
    v.x += t.x; v.y += t.y; v.z += t.z; v.w += t.w;
  }
  float sm = __logf(v.x) + __logf(v.y) + __logf(v.z) + __logf(v.w);
#pragma unroll
  for (int m = 1; m < 64; m <<= 1) sm += __shfl_xor(sm, m, 64);
  if (tid == 0) {
    atomicAdd(accum, sm);
    __threadfence();
    int prev = atomicAdd(cnt, 1);
    if (prev == (int)gridDim.x - 1) {
      __threadfence();
      float a = __hip_atomic_load(accum, __ATOMIC_RELAXED, __HIP_MEMORY_SCOPE_AGENT);
      out[0] = a / (float)NROWS;
    }
  }
}

extern "C" void kernel_launch(void* const* d_in, const int* in_sizes, int n_in,
                              void* d_out, int out_size, void* d_ws, size_t ws_size,
                              hipStream_t stream) {
  const float* x = (const float*)d_in[0];
  float* out = (float*)d_out;
  // ws layout: xbp 2 MB (fp8, fragment-packed) | rowpart 16x64KB | colpart 63x64KB | accum,cnt
  unsigned char* xbp = (unsigned char*)d_ws;
  float* rowpart = (float*)((char*)d_ws + (size_t)NROWS * DDIM);
  float* colpart = rowpart + (size_t)16 * NROWS;
  float* accum = colpart + (size_t)63 * NROWS;
  int* cnt = (int*)(accum + 1);

  convert_k<<<NROWS * DDIM / (256 * 4), 256, 0, stream>>>(x, xbp, accum, cnt);
  gram_tri_k<<<128 * 16, 256, 0, stream>>>(xbp, rowpart, colpart);
  finalize_k<<<NROWS / 256, 64, 0, stream>>>(rowpart, colpart, accum, cnt, out);
}

// Round 10
// 97.101 us; speedup vs baseline: 1.0875x; 1.0875x over previous
//
#include <hip/hip_runtime.h>
#include <math.h>

// Problem constants (reference: N=16384, D=128, T=0.07)
#define NROWS 16384
#define DDIM  128
constexpr float TEMP = 0.07f;
// Pre-scale trick: x *= sqrt(log2(e)/T) so MFMA emits acc = S*<xi,xj> and
// row_lse = ln(sum exp2(acc)). The DIAGONAL (sim_ii = 1 exactly) is masked
// out of the MFMA path and added analytically in finalize. Off-diag is only
// ~2.3% of rowsum, so fp8 e4m3 error there is damped ~44x.
constexpr float S_EXP = 1.44269504088896f / TEMP;  // 20.6099291

typedef __attribute__((ext_vector_type(16))) float f32x16;
typedef __attribute__((ext_vector_type(8)))  int   i32x8;

// Convert + pre-scale to fp8 e4m3, writing the 32x32x64 f8f6f4 FRAGMENT-
// PACKED layout: element (row, k) at byte
//   (panel<<14) | (rb<<12) | (km<<11) | (kh<<10) | (lr<<5) | j
// where panel=row>>7, rb=(row>>5)&3, lr=row&31, km=k>>6, kh=(k>>5)&1,
// j=k&31. MFMA operand layout: lane = kh*32 + lr holds 32 contiguous
// bytes (k = km*64 + kh*32 + j), so a wave's fragment load is ONE
// contiguous 2048 B region (lane*32) -> 2x global_load_dwordx4/lane,
// fully coalesced. Same buffer serves A (row panels) and B (col panels).
__global__ void convert_k(const float* __restrict__ x, unsigned char* __restrict__ xbp,
                          float* __restrict__ accum, int* __restrict__ cnt) {
  const float R = 4.53981419f;  // sqrt(S_EXP); |x*R| <= ~1.3, inside e4m3 range
  const int gid = blockIdx.x * blockDim.x + threadIdx.x;
  const int i = gid * 4;
  float4 v = *(const float4*)(x + i);
  int p = __builtin_amdgcn_cvt_pk_fp8_f32(v.x * R, v.y * R, 0, false);
  p = __builtin_amdgcn_cvt_pk_fp8_f32(v.z * R, v.w * R, p, true);
  const int row = i >> 7, k0 = i & 127;
  const int panel = row >> 7, rb = (row >> 5) & 3, lr = row & 31;
  const int km = k0 >> 6, kh = (k0 >> 5) & 1, j = k0 & 31;  // j 4-aligned
  *(int*)(xbp + ((size_t)panel << 14) + (rb << 12) + (km << 11) + (kh << 10) +
          (lr << 5) + j) = p;
  if (gid == 0) { *accum = 0.f; *cnt = 0; }
}

// Triangular Gram — ROUND-10: MX-scaled mfma_scale_f32_32x32x64_f8f6f4
// with unit scales (e8m0=127 -> x1.0): plain fp8 GEMM at 2.14x the
// 16x16x32 rate (4686 vs 2047 TF measured). Per wave-job the K-loop
// collapses 32 MFMA -> 4 (2 col-tiles x 2 K-halves), cutting the
// wave-blocking MFMA serial time from ~630 to ~275 cyc and MFMA-pipe
// demand from 17 to 7.4 us. r8/r9's zero-barrier loop + private csbuf
// slots + col-split 256-thr blocks retained (best verified structure).
// Block (I,ci,s): wave w owns rows w*32, cols ci*64 (2 tiles of 32).
// d-tiles s==0: d=0..8 else 8s+1..8s+8; J=(I+d)%128. d==0 diag masked;
// d in {0,64} col-slices skipped at store (mirror double-count).
// C/D layout 32x32 (shape-determined, m74/m101/m127): col = lane&31,
// row = (reg&3) + 8*(reg>>2) + 4*(lane>>5).
__global__ __launch_bounds__(256, 4)
void gram_tri_k(const unsigned char* __restrict__ xbp, float* __restrict__ rowpart,
                float* __restrict__ colpart) {
  __shared__ float csbuf[9][4][64];  // 9 KB: per-(tile,wave) col partials

  const int tid = threadIdx.x;
  const int w = tid >> 6, lane = tid & 63;
  const int l31 = lane & 31, lh = lane >> 5;
  const int I = (int)(blockIdx.x >> 4);
  const int ci = (int)((blockIdx.x >> 3) & 1);
  const int s = (int)(blockIdx.x & 7);
  const int rI = I * 128;
  const int dstart = (s == 0) ? 0 : 8 * s + 1;
  const int ntiles = (s == 0) ? 9 : 8;

  // A frags: rows w*32..w*32+31 of panel I; lane holds 32 B at lane*32
  i32x8 af[2];
  const unsigned char* gAb = xbp + ((size_t)I << 14) + (w << 12) + (lane << 5);
#pragma unroll
  for (int km = 0; km < 2; ++km)
    af[km] = *(const i32x8*)(gAb + (km << 11));

  // B lane base: col-tiles ci*2 + cb2 of panel J
  const unsigned char* gBlane = xbp + ((ci * 2) << 12) + (lane << 5);

  float rs[16];
#pragma unroll
  for (int r = 0; r < 16; ++r) rs[r] = 0.f;

  for (int ti = 0; ti < ntiles; ++ti) {
    const int d = dstart + ti;
    const unsigned char* gB = gBlane + ((size_t)((I + d) & 127) << 14);
    const bool dz = (d == 0);  // uniform; only s==0/ti==0 blocks pay the mask

    // all 4 B fragments up front (compiler hides L2 latency under MFMA)
    i32x8 bf[2][2];
#pragma unroll
    for (int cb2 = 0; cb2 < 2; ++cb2)
#pragma unroll
      for (int km = 0; km < 2; ++km)
        bf[cb2][km] = *(const i32x8*)(gB + (cb2 << 12) + (km << 11));

#pragma unroll
    for (int cb2 = 0; cb2 < 2; ++cb2) {
      f32x16 a;
#pragma unroll
      for (int z = 0; z < 16; ++z) a[z] = 0.f;
#pragma unroll
      for (int km = 0; km < 2; ++km)
        a = __builtin_amdgcn_mfma_scale_f32_32x32x64_f8f6f4(
            af[km], bf[cb2][km], a, 0 /*cbsz: fp8*/, 0 /*blgp: fp8*/,
            0, 127 /*scaleA = 2^0*/, 0, 127 /*scaleB = 2^0*/);
      // exp + accumulate; C/D: col = l31 (of this 32-tile), row = rowIdx
      float cst = 0.f;
#pragma unroll
      for (int r = 0; r < 16; ++r) {
        float e = __builtin_amdgcn_exp2f(a[r]);
        if (dz && (w * 32 + (r & 3) + 8 * (r >> 2) + 4 * lh) ==
                      (ci * 64 + cb2 * 32 + l31))
          e = 0.f;  // mask diagonal
        rs[r] += e;
        cst += e;
      }
      // col-sum: lane covers 16 rows of col l31; other 16 rows live in the
      // opposite lane-half -> one xor-32 shuffle completes the column.
      cst += __shfl_xor(cst, 32, 64);
      if (lh == 0) csbuf[ti][w][cb2 * 32 + l31] = cst;
    }
  }

  // row-sums: rs[r] on lane l = partials of row (r&3)+8*(r>>2)+4*lh over
  // cols {l31, 32+l31} of this wave's 64-col span (summed across tiles).
  // Reduce across the 32 lanes of each lane-half.
#pragma unroll
  for (int m = 1; m <= 16; m <<= 1)
#pragma unroll
    for (int r = 0; r < 16; ++r) rs[r] += __shfl_xor(rs[r], m, 64);
  if (l31 == 0) {
#pragma unroll
    for (int r = 0; r < 16; ++r)
      rowpart[(size_t)(ci * 8 + s) * NROWS + rI + w * 32 + (r & 3) + 8 * (r >> 2) +
              4 * lh] = rs[r];
  }

  __syncthreads();  // THE ONLY barrier: all csbuf slots complete

  // colpart stores: (ti, col) over this block's 64 cols, d not in {0,64}
  for (int e = tid; e < ntiles * 64; e += 256) {
    const int ti = e >> 6, col = e & 63;
    const int d = dstart + ti;
    if (d != 0 && d != 64)
      colpart[(size_t)(d - 1) * NROWS + ((I + d) & 127) * 128 + ci * 64 + col] =
          csbuf[ti][0][col] + csbuf[ti][1][col] + csbuf[ti][2][col] + csbuf[ti][3][col];
  }
}

// 64 blocks x 64 threads, 4 rows/thread via float4: sums 16 rowpart +
// 63 colpart slices, adds the analytic diagonal 2^S, logs, wave-reduces.
__global__ void finalize_k(const float* __restrict__ rowpart, const float* __restrict__ colpart,
                           float* __restrict__ accum, int* __restrict__ cnt,
                           float* __restrict__ out) {
  const int tid = threadIdx.x;
  const size_t i4 = (size_t)(blockIdx.x * 64 + tid) * 4;
  const float DIAG = __builtin_exp2f(S_EXP);  // exact e^{1/T}, rows unit-norm
  float4 v = {DIAG, DIAG, DIAG, DIAG};
#pragma unroll
  for (int s2 = 0; s2 < 16; ++s2) {
    float4 t = *(const float4*)&rowpart[(size_t)s2 * NROWS + i4];
    v.x += t.x; v.y += t.y; v.z += t.z; v.w += t.w;
  }
#pragma unroll
  for (int d = 1; d < 64; ++d) {
    float4 t = *(const float4*)&colpart[(size_t)(d - 1) * NROWS + i4];
    v.x += t.x; v.y += t.y; v.z += t.z; v.w += t.w;
  }
  float sm = __logf(v.x) + __logf(v.y) + __logf(v.z) + __logf(v.w);
#pragma unroll
  for (int m = 1; m < 64; m <<= 1) sm += __shfl_xor(sm, m, 64);
  if (tid == 0) {
    atomicAdd(accum, sm);
    __threadfence();
    int prev = atomicAdd(cnt, 1);
    if (prev == (int)gridDim.x - 1) {
      __threadfence();
      float a = __hip_atomic_load(accum, __ATOMIC_RELAXED, __HIP_MEMORY_SCOPE_AGENT);
      out[0] = a / (float)NROWS;
    }
  }
}

extern "C" void kernel_launch(void* const* d_in, const int* in_sizes, int n_in,
                              void* d_out, int out_size, void* d_ws, size_t ws_size,
                              hipStream_t stream) {
  const float* x = (const float*)d_in[0];
  float* out = (float*)d_out;
  // ws layout: xbp 2 MB (fp8, fragment-packed) | rowpart 16x64KB | colpart 63x64KB | accum,cnt
  unsigned char* xbp = (unsigned char*)d_ws;
  float* rowpart = (float*)((char*)d_ws + (size_t)NROWS * DDIM);
  float* colpart = rowpart + (size_t)16 * NROWS;
  float* accum = colpart + (size_t)63 * NROWS;
  int* cnt = (int*)(accum + 1);

  convert_k<<<NROWS * DDIM / (256 * 4), 256, 0, stream>>>(x, xbp, accum, cnt);
  gram_tri_k<<<128 * 16, 256, 0, stream>>>(xbp, rowpart, colpart);
  finalize_k<<<NROWS / 256, 64, 0, stream>>>(rowpart, colpart, accum, cnt, out);
}